// Round 3
// baseline (411.636 us; speedup 1.0000x reference)
//
#include <hip/hip_runtime.h>
#include <hip/hip_bf16.h>

#define N_NODES 50000
#define N_EDGES 800000
#define N_RELS 65
#define DIM 64
#define N_GRAPHS 512

#define SORT_BLOCKS 1024
#define CHUNK ((N_EDGES + SORT_BLOCKS - 1) / SORT_BLOCKS)  // 782

#define SCAN_BLK 512
#define NSCAN_BLKS ((N_NODES + SCAN_BLK - 1) / SCAN_BLK)   // 98

#define MSG_BLOCKS 2048
#define NWAVES (MSG_BLOCKS * 4)

typedef __attribute__((ext_vector_type(8))) short short8;
typedef __attribute__((ext_vector_type(4))) float f32x4;

// ================= prep 1: vectorized h conversion + zero counters =================

__global__ void conv_h_zero_kernel(const float* __restrict__ x, __hip_bfloat16* __restrict__ y,
                                   int* __restrict__ cnt_d, int* __restrict__ cnt_d2,
                                   int* __restrict__ cnt_g) {
    int i = blockIdx.x * 256 + threadIdx.x;
    if (i < (N_NODES * DIM) / 4) {
        float4 v = *(const float4*)(x + (size_t)i * 4);
        unsigned short us[4];
        us[0] = __hip_bfloat16_raw(__float2bfloat16(v.x)).x;
        us[1] = __hip_bfloat16_raw(__float2bfloat16(v.y)).x;
        us[2] = __hip_bfloat16_raw(__float2bfloat16(v.z)).x;
        us[3] = __hip_bfloat16_raw(__float2bfloat16(v.w)).x;
        *(ushort4*)(y + (size_t)i * 4) = *(const ushort4*)us;
    }
    if (i < N_NODES) { cnt_d[i] = 0; cnt_d2[i] = 0; }
    if (i < N_GRAPHS) cnt_g[i] = 0;
}

// ================= prep 1b: LDS-tiled W transpose (coalesced both sides) =================

__global__ __launch_bounds__(256) void wconv_kernel(
    const float* __restrict__ W1, const float* __restrict__ W2,
    const float* __restrict__ W3,
    __hip_bfloat16* __restrict__ Wt1, __hip_bfloat16* __restrict__ Wt2,
    __hip_bfloat16* __restrict__ Wt3) {
    __shared__ float tile[64][65];
    int b = blockIdx.x;                 // 0 .. 3*N_RELS-1
    int which = b / N_RELS, r = b - which * N_RELS;
    const float* W = (which == 0) ? W1 : (which == 1) ? W2 : W3;
    __hip_bfloat16* Wt = (which == 0) ? Wt1 : (which == 1) ? Wt2 : Wt3;
    int t = threadIdx.x;
    for (int i = t; i < 4096; i += 256) {
        int row = i >> 6, col = i & 63;          // row = d_in, col = d_out
        tile[row][col] = W[(size_t)r * 4096 + i];
    }
    __syncthreads();
    for (int i = t; i < 4096; i += 256) {
        int row = i >> 6, col = i & 63;          // row = d_out, col = d_in
        Wt[(size_t)r * 4096 + i] = __float2bfloat16(tile[col][row]);
    }
}

// ================= prep 2: rel-hist (transposed out) + graph counts =================

__global__ __launch_bounds__(256) void hist_all_kernel(
    const int* __restrict__ et, const int* __restrict__ gid,
    int* __restrict__ blk_hist, int* __restrict__ cnt_g) {
    __shared__ int lh[N_RELS];
    int t = threadIdx.x, b = blockIdx.x;
    int gtid = b * 256 + t;
    if (t < N_RELS) lh[t] = 0;
    __syncthreads();
    int lo = b * CHUNK;
    int hi = lo + CHUNK; if (hi > N_EDGES) hi = N_EDGES;
    for (int i = lo + t; i < hi; i += 256)
        atomicAdd(&lh[et[i]], 1);
    for (int i = gtid; i < N_NODES; i += SORT_BLOCKS * 256)
        atomicAdd(&cnt_g[gid[i]], 1);
    __syncthreads();
    if (t < N_RELS) blk_hist[t * SORT_BLOCKS + b] = lh[t];
}

// ================= prep 3a: per-relation scan — one block per relation =================

__global__ __launch_bounds__(256) void relscan_kernel(const int* __restrict__ blk_hist,
                                                      int* __restrict__ blk_off,
                                                      int* __restrict__ rel_tot) {
    __shared__ int wsum[4];
    int r = blockIdx.x;
    int t = threadIdx.x;
    int w = t >> 6, lane = t & 63;
    const int PER = SORT_BLOCKS / 256;  // 4
    int4 v0 = *(const int4*)(blk_hist + (size_t)r * SORT_BLOCKS + t * PER);
    int vals[4] = {v0.x, v0.y, v0.z, v0.w};
    int s = 0;
    #pragma unroll
    for (int j = 0; j < PER; ++j) s += vals[j];
    // wave-inclusive scan of per-thread sums
    int x = s;
    #pragma unroll
    for (int off = 1; off < 64; off <<= 1) {
        int y = __shfl_up(x, off);
        if (lane >= off) x += y;
    }
    if (lane == 63) wsum[w] = x;
    __syncthreads();
    int base = 0;
    for (int i = 0; i < w; ++i) base += wsum[i];
    int run = base + x - s;  // exclusive prefix for this thread's first entry
    int out[4];
    #pragma unroll
    for (int j = 0; j < PER; ++j) { out[j] = run; run += vals[j]; }
    *(int4*)(blk_off + (size_t)r * SORT_BLOCKS + t * PER) = *(const int4*)&out[0];
    if (t == 255) rel_tot[r] = base + x;
}

// ================= prep 3b: tiny cross-relation scan =================

__global__ __launch_bounds__(64) void reltop_kernel(const int* __restrict__ rel_tot,
                                                    int* __restrict__ rel_ptr,
                                                    int* __restrict__ tile_base) {
    if (threadIdx.x == 0) {
        int s = 0, tt = 0;
        for (int q = 0; q < N_RELS; ++q) {
            int v = rel_tot[q];
            rel_ptr[q] = s; s += v;
            tile_base[q] = tt; tt += (v + 15) >> 4;
        }
        rel_ptr[N_RELS] = N_EDGES;
        tile_base[N_RELS] = tt;
    }
}

// ================= prep 4: scatter (4B packed) + fire-and-forget dst count =================

__global__ __launch_bounds__(256) void scatter2_kernel(
    const int* __restrict__ et, const int* __restrict__ src,
    const int* __restrict__ dst, const int* __restrict__ blk_off,
    const int* __restrict__ rel_ptr,
    unsigned* __restrict__ epk, int* __restrict__ cnt_d) {
    __shared__ int cur[N_RELS];
    int t = threadIdx.x, b = blockIdx.x;
    if (t < N_RELS) cur[t] = blk_off[t * SORT_BLOCKS + b] + rel_ptr[t];
    __syncthreads();
    int lo = b * CHUNK;
    int hi = lo + CHUNK; if (hi > N_EDGES) hi = N_EDGES;

    bool val[4]; int rr[4], dd[4]; unsigned ss[4];
    #pragma unroll
    for (int k = 0; k < 4; ++k) {
        int i = lo + t + k * 256;
        val[k] = (i < hi);
        int ic = val[k] ? i : lo;
        rr[k] = et[ic]; dd[k] = dst[ic]; ss[k] = (unsigned)src[ic];
    }
    // degree count: no return value needed -> fire-and-forget, no latency chain
    #pragma unroll
    for (int k = 0; k < 4; ++k)
        if (val[k]) atomicAdd(&cnt_d[dd[k]], 1);
    int p[4];
    #pragma unroll
    for (int k = 0; k < 4; ++k)
        if (val[k]) p[k] = atomicAdd(&cur[rr[k]], 1);
    #pragma unroll
    for (int k = 0; k < 4; ++k)
        if (val[k])
            epk[p[k]] = ss[k] | ((unsigned)dd[k] << 16);
}

// ================= prep 5-8: dst CSR scan + graph segments + unpack(+rank) =================

__global__ __launch_bounds__(SCAN_BLK) void scanblk_kernel(const int* __restrict__ cnt,
                                                           int* __restrict__ outv,
                                                           int* __restrict__ blk_tot) {
    __shared__ int tmp[SCAN_BLK];
    int t = threadIdx.x;
    int i = blockIdx.x * SCAN_BLK + t;
    int v = (i < N_NODES) ? cnt[i] : 0;
    tmp[t] = v;
    __syncthreads();
    for (int off = 1; off < SCAN_BLK; off <<= 1) {
        int add = (t >= off) ? tmp[t - off] : 0;
        __syncthreads();
        tmp[t] += add;
        __syncthreads();
    }
    if (i < N_NODES) outv[i] = tmp[t] - v;  // exclusive
    if (t == SCAN_BLK - 1) blk_tot[blockIdx.x] = tmp[t];
}

__global__ __launch_bounds__(64) void scantop_gid_kernel(
    const int* __restrict__ blk_tot, int* __restrict__ blk_base,
    const int* __restrict__ cnt_g, int* __restrict__ g_ptr) {
    int lane = threadIdx.x;
    if (blockIdx.x == 0) {
        if (lane == 0) {
            int run = 0;
            for (int b = 0; b < NSCAN_BLKS; ++b) { blk_base[b] = run; run += blk_tot[b]; }
        }
    } else {
        int run = 0;
        for (int c = 0; c < N_GRAPHS; c += 64) {
            int v = cnt_g[c + lane];
            int x = v;
            #pragma unroll
            for (int off = 1; off < 64; off <<= 1) {
                int y = __shfl_up(x, off);
                if (lane >= off) x += y;
            }
            g_ptr[c + lane] = run + x - v;
            run += __shfl(x, 63);
        }
    }
}

__global__ __launch_bounds__(SCAN_BLK) void scanadd_kernel(int* __restrict__ outv,
                                                           const int* __restrict__ blk_base) {
    int i = blockIdx.x * SCAN_BLK + threadIdx.x;
    if (i < N_NODES) outv[i] += blk_base[blockIdx.x];
}

// rank assignment moved here: streaming kernel, 1 edge/thread, atomic latency hidden by TLP
__global__ void unpack_kernel(const unsigned* __restrict__ epk,
                              const int* __restrict__ row_ptr,
                              int* __restrict__ cnt_d2,
                              int* __restrict__ src_s, int* __restrict__ dpos) {
    int i = blockIdx.x * 256 + threadIdx.x;
    if (i < N_EDGES) {
        unsigned e = epk[i];
        int s = (int)(e & 0xFFFFu);
        int d = (int)(e >> 16);
        int rank = atomicAdd(&cnt_d2[d], 1);
        src_s[i] = s;
        dpos[i] = rank + row_ptr[d];
    }
}

// ================= phase 1: MFMA message kernel — zero-LDS, 4-col-interleaved B,
//                   single 8B packed store per row-group =================

__device__ inline unsigned pack2bf(float x, float y) {
    unsigned short ux = __hip_bfloat16_raw(__float2bfloat16(x)).x;
    unsigned short uy = __hip_bfloat16_raw(__float2bfloat16(y)).x;
    return (unsigned)ux | ((unsigned)uy << 16);
}

__global__ __launch_bounds__(256) void msg_mfma_kernel(
    const __hip_bfloat16* __restrict__ hb, const __hip_bfloat16* __restrict__ Wt,
    const int* __restrict__ rel_ptr, const int* __restrict__ tile_base,
    const int* __restrict__ src_s, const int* __restrict__ dpos,
    __hip_bfloat16* __restrict__ msg) {
    int t = threadIdx.x;
    int w = t >> 6, lane = t & 63;
    int quad = lane >> 4, m16 = lane & 15;
    int wave = blockIdx.x * 4 + w;

    int ntiles = tile_base[N_RELS];
    int tpw = (ntiles + NWAVES - 1) / NWAVES;
    int T = wave * tpw;
    int T1 = T + tpw; if (T1 > ntiles) T1 = ntiles;
    if (T >= T1) return;

    int r = 0;
    while (T >= tile_base[r + 1]) ++r;

    while (T < T1) {
        int chunk_end = tile_base[r + 1]; if (chunk_end > T1) chunk_end = T1;
        int e_base = rel_ptr[r], t_base = tile_base[r];
        int seg_end = rel_ptr[r + 1];

        // B fragments with 4-col interleave: MFMA tile j computes true output
        // col 4*m16 + j. A lane's (c0,c1,c2,c3)[g] are then 4 CONSECUTIVE true
        // columns -> pack into 2 dwords, single 8B store; a quad's 16 lanes
        // cover a fully contiguous 128B msg row.
        const __hip_bfloat16* Wr = Wt + (size_t)r * (DIM * DIM);
        short8 bf00 = *(const short8*)(Wr + (4 * m16)     * DIM + quad * 8);
        short8 bf01 = *(const short8*)(Wr + (4 * m16 + 1) * DIM + quad * 8);
        short8 bf02 = *(const short8*)(Wr + (4 * m16 + 2) * DIM + quad * 8);
        short8 bf03 = *(const short8*)(Wr + (4 * m16 + 3) * DIM + quad * 8);
        short8 bf10 = *(const short8*)(Wr + (4 * m16)     * DIM + 32 + quad * 8);
        short8 bf11 = *(const short8*)(Wr + (4 * m16 + 1) * DIM + 32 + quad * 8);
        short8 bf12 = *(const short8*)(Wr + (4 * m16 + 2) * DIM + 32 + quad * 8);
        short8 bf13 = *(const short8*)(Wr + (4 * m16 + 3) * DIM + 32 + quad * 8);

        auto loadidx = [&](int TT, int& sv, int& dp) {
            int TC = TT < chunk_end ? TT : chunk_end - 1;
            int i = e_base + (TC - t_base) * 16 + lane;
            if (i >= N_EDGES) i = N_EDGES - 1;
            sv = src_s[i]; dp = dpos[i];
        };
        // Gather A directly in MFMA fragment layout: row = m16, k = quad*8 + j.
        auto gatherA = [&](int sv, short8& x0, short8& x1) {
            int s = __shfl(sv, m16);
            const __hip_bfloat16* hp = hb + (size_t)s * DIM + quad * 8;
            x0 = *(const short8*)hp;
            x1 = *(const short8*)(hp + 32);
        };

        int sv0, dp0, sv1, dp1, sv2, dp2;
        short8 a0c, a1c, a0n, a1n;
        loadidx(T,     sv0, dp0);
        loadidx(T + 1, sv1, dp1);
        gatherA(sv0, a0c, a1c);

        for (; T < chunk_end; ++T) {
            loadidx(T + 2, sv2, dp2);
            gatherA(sv1, a0n, a1n);

            int e0 = e_base + (T - t_base) * 16;
            int rows = seg_end - e0; if (rows > 16) rows = 16;

            f32x4 c0 = {0.f, 0.f, 0.f, 0.f}, c1 = c0, c2 = c0, c3 = c0;
            c0 = __builtin_amdgcn_mfma_f32_16x16x32_bf16(a0c, bf00, c0, 0, 0, 0);
            c1 = __builtin_amdgcn_mfma_f32_16x16x32_bf16(a0c, bf01, c1, 0, 0, 0);
            c2 = __builtin_amdgcn_mfma_f32_16x16x32_bf16(a0c, bf02, c2, 0, 0, 0);
            c3 = __builtin_amdgcn_mfma_f32_16x16x32_bf16(a0c, bf03, c3, 0, 0, 0);
            c0 = __builtin_amdgcn_mfma_f32_16x16x32_bf16(a1c, bf10, c0, 0, 0, 0);
            c1 = __builtin_amdgcn_mfma_f32_16x16x32_bf16(a1c, bf11, c1, 0, 0, 0);
            c2 = __builtin_amdgcn_mfma_f32_16x16x32_bf16(a1c, bf12, c2, 0, 0, 0);
            c3 = __builtin_amdgcn_mfma_f32_16x16x32_bf16(a1c, bf13, c3, 0, 0, 0);

            // C layout: row = quad*4+g, tile-col = m16 -> true cols 4*m16..4*m16+3.
            int dpr[4];
            #pragma unroll
            for (int g = 0; g < 4; ++g) dpr[g] = __shfl(dp0, quad * 4 + g);

            #pragma unroll
            for (int g = 0; g < 4; ++g) {
                if (quad * 4 + g < rows) {
                    uint2 pk;
                    pk.x = pack2bf(c0[g], c1[g]);
                    pk.y = pack2bf(c2[g], c3[g]);
                    *(uint2*)(msg + (size_t)dpr[g] * DIM + 4 * m16) = pk;
                }
            }

            sv0 = sv1; dp0 = dp1; sv1 = sv2; dp1 = dp2;
            a0c = a0n; a1c = a1n;
        }
        ++r;
        while (T < T1 && T >= tile_base[r + 1]) ++r;
    }
}

// ================= phase 2: vectorized pull-aggregate + bias + ReLU =================

__global__ __launch_bounds__(256) void agg_kernel(
    const __hip_bfloat16* __restrict__ msg, const int* __restrict__ row_ptr,
    const int* __restrict__ cnt_d, const float* __restrict__ b,
    __hip_bfloat16* __restrict__ hout) {
    int wave = blockIdx.x * 4 + (threadIdx.x >> 6);
    int lane = threadIdx.x & 63;
    if (wave >= N_NODES) return;
    int j0 = row_ptr[wave];
    int n  = cnt_d[wave];
    int rgrp = lane >> 3, dgrp = lane & 7;

    float a[8] = {0.f, 0.f, 0.f, 0.f, 0.f, 0.f, 0.f, 0.f};
    for (int jj = 0; jj < n; jj += 8) {
        int row = jj + rgrp;
        if (row < n) {
            uint4 d = *(const uint4*)(msg + (size_t)(j0 + row) * DIM + dgrp * 8);
            a[0] += __uint_as_float(d.x << 16);
            a[1] += __uint_as_float(d.x & 0xffff0000u);
            a[2] += __uint_as_float(d.y << 16);
            a[3] += __uint_as_float(d.y & 0xffff0000u);
            a[4] += __uint_as_float(d.z << 16);
            a[5] += __uint_as_float(d.z & 0xffff0000u);
            a[6] += __uint_as_float(d.w << 16);
            a[7] += __uint_as_float(d.w & 0xffff0000u);
        }
    }
    #pragma unroll
    for (int i = 0; i < 8; ++i) {
        a[i] += __shfl_xor(a[i], 8);
        a[i] += __shfl_xor(a[i], 16);
        a[i] += __shfl_xor(a[i], 32);
    }
    if (rgrp == 0) {
        unsigned short us[8];
        #pragma unroll
        for (int i = 0; i < 8; ++i) {
            float v = a[i] + b[dgrp * 8 + i];
            us[i] = __hip_bfloat16_raw(__float2bfloat16(v > 0.f ? v : 0.f)).x;
        }
        *(uint4*)(hout + (size_t)wave * DIM + dgrp * 8) = *(const uint4*)us;
    }
}

// ================= fused pool + FC x3 + prediction head =================

__global__ __launch_bounds__(256) void poolfc_kernel(
    const __hip_bfloat16* __restrict__ h, const int* __restrict__ g_ptr,
    const int* __restrict__ cnt_g,
    const float* __restrict__ W1, const float* __restrict__ b1,
    const float* __restrict__ W2, const float* __restrict__ b2,
    const float* __restrict__ W3, const float* __restrict__ b3,
    const float* __restrict__ pW, const float* __restrict__ pb,
    float* __restrict__ out) {
    int wave = blockIdx.x * 4 + (threadIdx.x >> 6);
    int lane = threadIdx.x & 63;
    if (wave >= N_GRAPHS) return;
    int j0 = g_ptr[wave];
    int n  = cnt_g[wave];
    int rgrp = lane >> 3, dgrp = lane & 7;

    float a[8] = {0.f, 0.f, 0.f, 0.f, 0.f, 0.f, 0.f, 0.f};
    for (int jj = 0; jj < n; jj += 8) {
        int row = jj + rgrp;
        if (row < n) {
            uint4 d = *(const uint4*)(h + (size_t)(j0 + row) * DIM + dgrp * 8);
            a[0] += __uint_as_float(d.x << 16);
            a[1] += __uint_as_float(d.x & 0xffff0000u);
            a[2] += __uint_as_float(d.y << 16);
            a[3] += __uint_as_float(d.y & 0xffff0000u);
            a[4] += __uint_as_float(d.z << 16);
            a[5] += __uint_as_float(d.z & 0xffff0000u);
            a[6] += __uint_as_float(d.w << 16);
            a[7] += __uint_as_float(d.w & 0xffff0000u);
        }
    }
    #pragma unroll
    for (int i = 0; i < 8; ++i) {
        a[i] += __shfl_xor(a[i], 8);
        a[i] += __shfl_xor(a[i], 16);
        a[i] += __shfl_xor(a[i], 32);
    }
    float v;
    {
        float acc = b1[lane];
        #pragma unroll
        for (int o = 0; o < 8; ++o)
            #pragma unroll
            for (int q = 0; q < 8; ++q)
                acc += __shfl(a[o], q) * W1[(q * 8 + o) * DIM + lane];
        v = acc > 0.f ? acc : 0.f;
    }
    {
        float acc = b2[lane];
        #pragma unroll
        for (int d = 0; d < DIM; ++d)
            acc += __shfl(v, d) * W2[d * DIM + lane];
        v = acc > 0.f ? acc : 0.f;
    }
    {
        float acc = b3[lane];
        #pragma unroll
        for (int d = 0; d < DIM; ++d)
            acc += __shfl(v, d) * W3[d * DIM + lane];
        v = acc > 0.f ? acc : 0.f;
    }
    float p0 = v * pW[lane * 2 + 0];
    float p1 = v * pW[lane * 2 + 1];
    #pragma unroll
    for (int off = 32; off > 0; off >>= 1) {
        p0 += __shfl_down(p0, off);
        p1 += __shfl_down(p1, off);
    }
    if (lane == 0) {
        out[wave * 2 + 0] = p0 + pb[0];
        out[wave * 2 + 1] = p1 + pb[1];
    }
}

// ================= launch =================

extern "C" void kernel_launch(void* const* d_in, const int* in_sizes, int n_in,
                              void* d_out, int out_size, void* d_ws, size_t ws_size,
                              hipStream_t stream) {
    const float* node_feats = (const float*)d_in[0];
    const int*   etypes     = (const int*)d_in[1];
    const int*   src        = (const int*)d_in[2];
    const int*   dst        = (const int*)d_in[3];
    const int*   graph_ids  = (const int*)d_in[4];
    const float* W1 = (const float*)d_in[5];
    const float* b1 = (const float*)d_in[6];
    const float* W2 = (const float*)d_in[7];
    const float* b2 = (const float*)d_in[8];
    const float* W3 = (const float*)d_in[9];
    const float* b3 = (const float*)d_in[10];
    const float* fcW1 = (const float*)d_in[11];
    const float* fcb1 = (const float*)d_in[12];
    const float* fcW2 = (const float*)d_in[13];
    const float* fcb2 = (const float*)d_in[14];
    const float* fcW3 = (const float*)d_in[15];
    const float* fcb3 = (const float*)d_in[16];
    const float* pW = (const float*)d_in[17];
    const float* pb = (const float*)d_in[18];
    float* out = (float*)d_out;

    // workspace carve-up (256B aligned)
    char* p = (char*)d_ws;
    auto alloc = [&](size_t bytes) -> void* {
        void* r = (void*)p;
        p += (bytes + 255) & ~(size_t)255;
        return r;
    };
    int* blk_hist  = (int*)alloc((size_t)SORT_BLOCKS * N_RELS * sizeof(int));
    int* blk_off   = (int*)alloc((size_t)SORT_BLOCKS * N_RELS * sizeof(int));
    int* rel_ptr   = (int*)alloc((N_RELS + 1) * sizeof(int));
    int* rel_tot   = (int*)alloc(N_RELS * sizeof(int));
    int* tile_base = (int*)alloc((N_RELS + 1) * sizeof(int));
    unsigned* epk  = (unsigned*)alloc((size_t)N_EDGES * sizeof(unsigned));
    int* src_s     = (int*)alloc((size_t)N_EDGES * sizeof(int));
    int* dpos      = (int*)alloc((size_t)N_EDGES * sizeof(int));
    int* cnt_d     = (int*)alloc((size_t)N_NODES * sizeof(int));
    int* cnt_d2    = (int*)alloc((size_t)N_NODES * sizeof(int));
    int* row_ptr   = (int*)alloc((size_t)N_NODES * sizeof(int));
    int* blk_tot   = (int*)alloc(NSCAN_BLKS * sizeof(int));
    int* blk_base  = (int*)alloc(NSCAN_BLKS * sizeof(int));
    int* cnt_g     = (int*)alloc(N_GRAPHS * sizeof(int));
    int* g_ptr     = (int*)alloc(N_GRAPHS * sizeof(int));
    __hip_bfloat16* hb0 = (__hip_bfloat16*)alloc((size_t)N_NODES * DIM * sizeof(__hip_bfloat16));
    __hip_bfloat16* hb1 = (__hip_bfloat16*)alloc((size_t)N_NODES * DIM * sizeof(__hip_bfloat16));
    __hip_bfloat16* Wt1 = (__hip_bfloat16*)alloc((size_t)N_RELS * DIM * DIM * sizeof(__hip_bfloat16));
    __hip_bfloat16* Wt2 = (__hip_bfloat16*)alloc((size_t)N_RELS * DIM * DIM * sizeof(__hip_bfloat16));
    __hip_bfloat16* Wt3 = (__hip_bfloat16*)alloc((size_t)N_RELS * DIM * DIM * sizeof(__hip_bfloat16));
    __hip_bfloat16* msg = (__hip_bfloat16*)alloc((size_t)N_EDGES * DIM * sizeof(__hip_bfloat16));

    const int EBLK = (N_EDGES + 255) / 256;              // 3125
    const int CBLK = (N_NODES * DIM / 4 + 255) / 256;    // 3125
    const int AGG_BLOCKS = (N_NODES + 3) / 4;            // 12500

    // ---- prep ----
    conv_h_zero_kernel<<<CBLK, 256, 0, stream>>>(node_feats, hb0, cnt_d, cnt_d2, cnt_g);
    wconv_kernel<<<3 * N_RELS, 256, 0, stream>>>(W1, W2, W3, Wt1, Wt2, Wt3);
    hist_all_kernel<<<SORT_BLOCKS, 256, 0, stream>>>(etypes, graph_ids, blk_hist, cnt_g);
    relscan_kernel<<<N_RELS, 256, 0, stream>>>(blk_hist, blk_off, rel_tot);
    reltop_kernel<<<1, 64, 0, stream>>>(rel_tot, rel_ptr, tile_base);
    scatter2_kernel<<<SORT_BLOCKS, 256, 0, stream>>>(etypes, src, dst, blk_off, rel_ptr,
                                                     epk, cnt_d);
    scanblk_kernel<<<NSCAN_BLKS, SCAN_BLK, 0, stream>>>(cnt_d, row_ptr, blk_tot);
    scantop_gid_kernel<<<2, 64, 0, stream>>>(blk_tot, blk_base, cnt_g, g_ptr);
    scanadd_kernel<<<NSCAN_BLKS, SCAN_BLK, 0, stream>>>(row_ptr, blk_base);
    unpack_kernel<<<EBLK, 256, 0, stream>>>(epk, row_ptr, cnt_d2, src_s, dpos);

    // ---- 3 RGCN layers ----
    msg_mfma_kernel<<<MSG_BLOCKS, 256, 0, stream>>>(hb0, Wt1, rel_ptr, tile_base,
                                                    src_s, dpos, msg);
    agg_kernel<<<AGG_BLOCKS, 256, 0, stream>>>(msg, row_ptr, cnt_d, b1, hb1);

    msg_mfma_kernel<<<MSG_BLOCKS, 256, 0, stream>>>(hb1, Wt2, rel_ptr, tile_base,
                                                    src_s, dpos, msg);
    agg_kernel<<<AGG_BLOCKS, 256, 0, stream>>>(msg, row_ptr, cnt_d, b2, hb0);

    msg_mfma_kernel<<<MSG_BLOCKS, 256, 0, stream>>>(hb0, Wt3, rel_ptr, tile_base,
                                                    src_s, dpos, msg);
    agg_kernel<<<AGG_BLOCKS, 256, 0, stream>>>(msg, row_ptr, cnt_d, b3, hb1);

    // ---- fused pool + FC head ----
    poolfc_kernel<<<(N_GRAPHS + 3) / 4, 256, 0, stream>>>(hb1, g_ptr, cnt_g,
                                                          fcW1, fcb1, fcW2, fcb2,
                                                          fcW3, fcb3, pW, pb, out);
}

// Round 4
// 383.429 us; speedup vs baseline: 1.0736x; 1.0736x over previous
//
#include <hip/hip_runtime.h>
#include <hip/hip_bf16.h>

#define N_NODES 50000
#define N_EDGES 800000
#define N_RELS 65
#define DIM 64
#define N_GRAPHS 512

#define SORT_BLOCKS 1024
#define CHUNK ((N_EDGES + SORT_BLOCKS - 1) / SORT_BLOCKS)  // 782

#define SCAN_BLK 512
#define NSCAN_BLKS ((N_NODES + SCAN_BLK - 1) / SCAN_BLK)   // 98

#define MSG_BLOCKS 2048
#define NWAVES (MSG_BLOCKS * 4)

typedef __attribute__((ext_vector_type(8))) short short8;
typedef __attribute__((ext_vector_type(4))) float f32x4;

// ================= prep 1: vectorized h conversion + zero counters =================

__global__ void conv_h_zero_kernel(const float* __restrict__ x, __hip_bfloat16* __restrict__ y,
                                   int* __restrict__ cnt_d, int* __restrict__ cnt_g) {
    int i = blockIdx.x * 256 + threadIdx.x;
    if (i < (N_NODES * DIM) / 4) {
        float4 v = *(const float4*)(x + (size_t)i * 4);
        unsigned short us[4];
        us[0] = __hip_bfloat16_raw(__float2bfloat16(v.x)).x;
        us[1] = __hip_bfloat16_raw(__float2bfloat16(v.y)).x;
        us[2] = __hip_bfloat16_raw(__float2bfloat16(v.z)).x;
        us[3] = __hip_bfloat16_raw(__float2bfloat16(v.w)).x;
        *(ushort4*)(y + (size_t)i * 4) = *(const ushort4*)us;
    }
    if (i < N_NODES) cnt_d[i] = 0;
    if (i < N_GRAPHS) cnt_g[i] = 0;
}

// ================= prep 1b: LDS-tiled W transpose (coalesced both sides) =================

__global__ __launch_bounds__(256) void wconv_kernel(
    const float* __restrict__ W1, const float* __restrict__ W2,
    const float* __restrict__ W3,
    __hip_bfloat16* __restrict__ Wt1, __hip_bfloat16* __restrict__ Wt2,
    __hip_bfloat16* __restrict__ Wt3) {
    __shared__ float tile[64][65];
    int b = blockIdx.x;                 // 0 .. 3*N_RELS-1
    int which = b / N_RELS, r = b - which * N_RELS;
    const float* W = (which == 0) ? W1 : (which == 1) ? W2 : W3;
    __hip_bfloat16* Wt = (which == 0) ? Wt1 : (which == 1) ? Wt2 : Wt3;
    int t = threadIdx.x;
    for (int i = t; i < 4096; i += 256) {
        int row = i >> 6, col = i & 63;          // row = d_in, col = d_out
        tile[row][col] = W[(size_t)r * 4096 + i];
    }
    __syncthreads();
    for (int i = t; i < 4096; i += 256) {
        int row = i >> 6, col = i & 63;          // row = d_out, col = d_in
        Wt[(size_t)r * 4096 + i] = __float2bfloat16(tile[col][row]);
    }
}

// ================= prep 2: rel-hist (transposed out) + graph counts =================

__global__ __launch_bounds__(256) void hist_all_kernel(
    const int* __restrict__ et, const int* __restrict__ gid,
    int* __restrict__ blk_hist, int* __restrict__ cnt_g) {
    __shared__ int lh[N_RELS];
    int t = threadIdx.x, b = blockIdx.x;
    int gtid = b * 256 + t;
    if (t < N_RELS) lh[t] = 0;
    __syncthreads();
    int lo = b * CHUNK;
    int hi = lo + CHUNK; if (hi > N_EDGES) hi = N_EDGES;
    for (int i = lo + t; i < hi; i += 256)
        atomicAdd(&lh[et[i]], 1);
    for (int i = gtid; i < N_NODES; i += SORT_BLOCKS * 256)
        atomicAdd(&cnt_g[gid[i]], 1);
    __syncthreads();
    if (t < N_RELS) blk_hist[t * SORT_BLOCKS + b] = lh[t];
}

// ================= prep 3a: per-relation scan — one block per relation =================

__global__ __launch_bounds__(256) void relscan_kernel(const int* __restrict__ blk_hist,
                                                      int* __restrict__ blk_off,
                                                      int* __restrict__ rel_tot) {
    __shared__ int wsum[4];
    int r = blockIdx.x;
    int t = threadIdx.x;
    int w = t >> 6, lane = t & 63;
    const int PER = SORT_BLOCKS / 256;  // 4
    int4 v0 = *(const int4*)(blk_hist + (size_t)r * SORT_BLOCKS + t * PER);
    int vals[4] = {v0.x, v0.y, v0.z, v0.w};
    int s = 0;
    #pragma unroll
    for (int j = 0; j < PER; ++j) s += vals[j];
    // wave-inclusive scan of per-thread sums
    int x = s;
    #pragma unroll
    for (int off = 1; off < 64; off <<= 1) {
        int y = __shfl_up(x, off);
        if (lane >= off) x += y;
    }
    if (lane == 63) wsum[w] = x;
    __syncthreads();
    int base = 0;
    for (int i = 0; i < w; ++i) base += wsum[i];
    int run = base + x - s;  // exclusive prefix for this thread's first entry
    int out[4];
    #pragma unroll
    for (int j = 0; j < PER; ++j) { out[j] = run; run += vals[j]; }
    *(int4*)(blk_off + (size_t)r * SORT_BLOCKS + t * PER) = *(const int4*)&out[0];
    if (t == 255) rel_tot[r] = base + x;
}

// ================= prep 3b: tiny cross-relation scan =================

__global__ __launch_bounds__(64) void reltop_kernel(const int* __restrict__ rel_tot,
                                                    int* __restrict__ rel_ptr,
                                                    int* __restrict__ tile_base) {
    if (threadIdx.x == 0) {
        int s = 0, tt = 0;
        for (int q = 0; q < N_RELS; ++q) {
            int v = rel_tot[q];
            rel_ptr[q] = s; s += v;
            tile_base[q] = tt; tt += (v + 15) >> 4;
        }
        rel_ptr[N_RELS] = N_EDGES;
        tile_base[N_RELS] = tt;
    }
}

// ================= prep 4: LDS-staged counting-sort scatter + fused rank =================
// Stage edges rel-sorted in LDS, then copy LDS->global linearly: consecutive
// threads write consecutive addresses within each rel run (avg 96B) instead of
// random 8B stores (5x write amplification observed in R0/R2).

__global__ __launch_bounds__(256) void scatter2_kernel(
    const int* __restrict__ et, const int* __restrict__ src,
    const int* __restrict__ dst, const int* __restrict__ blk_hist,
    const int* __restrict__ blk_off, const int* __restrict__ rel_ptr,
    unsigned long long* __restrict__ epk, int* __restrict__ cnt_d) {
    __shared__ unsigned long long buf[CHUNK];
    __shared__ unsigned char relof[CHUNK];
    __shared__ int loff[N_RELS + 1];
    __shared__ int lcur[N_RELS];
    __shared__ int gbase[N_RELS];
    int t = threadIdx.x, b = blockIdx.x;

    // local exclusive scan of this block's 65-bin histogram (wave 0)
    if (t < 64) {
        int v = blk_hist[t * SORT_BLOCKS + b];
        int x = v;
        #pragma unroll
        for (int off = 1; off < 64; off <<= 1) {
            int y = __shfl_up(x, off);
            if (t >= off) x += y;
        }
        loff[t] = x - v;
        lcur[t] = x - v;
        gbase[t] = rel_ptr[t] + blk_off[t * SORT_BLOCKS + b];
        if (t == 63) { loff[64] = x; lcur[64] = x; }
    } else if (t == 64) {
        gbase[64] = rel_ptr[64] + blk_off[64 * SORT_BLOCKS + b];
    }
    __syncthreads();

    int lo = b * CHUNK;
    int hi = lo + CHUNK; if (hi > N_EDGES) hi = N_EDGES;
    int nloc = hi - lo;

    // phase B: rank (single returning atomic = degree count AND rank) + LDS scatter
    #pragma unroll
    for (int k = 0; k < 4; ++k) {
        int i = lo + t + k * 256;
        if (i < hi) {
            int r = et[i], d = dst[i];
            unsigned s = (unsigned)src[i];
            int rank = atomicAdd(&cnt_d[d], 1);
            int pl = atomicAdd(&lcur[r], 1);
            unsigned lo32 = s | ((unsigned)d << 16);
            buf[pl] = (unsigned long long)lo32 |
                      ((unsigned long long)(unsigned)rank << 32);
            relof[pl] = (unsigned char)r;
        }
    }
    __syncthreads();

    // phase C: linear LDS->global copy; within-run stores are consecutive
    #pragma unroll
    for (int k = 0; k < 4; ++k) {
        int i = t + k * 256;
        if (i < nloc) {
            int r = relof[i];
            epk[gbase[r] + i - loff[r]] = buf[i];
        }
    }
}

// ================= prep 5-8: dst CSR scan + graph segments + unpack =================

__global__ __launch_bounds__(SCAN_BLK) void scanblk_kernel(const int* __restrict__ cnt,
                                                           int* __restrict__ outv,
                                                           int* __restrict__ blk_tot) {
    __shared__ int tmp[SCAN_BLK];
    int t = threadIdx.x;
    int i = blockIdx.x * SCAN_BLK + t;
    int v = (i < N_NODES) ? cnt[i] : 0;
    tmp[t] = v;
    __syncthreads();
    for (int off = 1; off < SCAN_BLK; off <<= 1) {
        int add = (t >= off) ? tmp[t - off] : 0;
        __syncthreads();
        tmp[t] += add;
        __syncthreads();
    }
    if (i < N_NODES) outv[i] = tmp[t] - v;  // exclusive
    if (t == SCAN_BLK - 1) blk_tot[blockIdx.x] = tmp[t];
}

__global__ __launch_bounds__(64) void scantop_gid_kernel(
    const int* __restrict__ blk_tot, int* __restrict__ blk_base,
    const int* __restrict__ cnt_g, int* __restrict__ g_ptr) {
    int lane = threadIdx.x;
    if (blockIdx.x == 0) {
        if (lane == 0) {
            int run = 0;
            for (int b = 0; b < NSCAN_BLKS; ++b) { blk_base[b] = run; run += blk_tot[b]; }
        }
    } else {
        int run = 0;
        for (int c = 0; c < N_GRAPHS; c += 64) {
            int v = cnt_g[c + lane];
            int x = v;
            #pragma unroll
            for (int off = 1; off < 64; off <<= 1) {
                int y = __shfl_up(x, off);
                if (lane >= off) x += y;
            }
            g_ptr[c + lane] = run + x - v;
            run += __shfl(x, 63);
        }
    }
}

__global__ __launch_bounds__(SCAN_BLK) void scanadd_kernel(int* __restrict__ outv,
                                                           const int* __restrict__ blk_base) {
    int i = blockIdx.x * SCAN_BLK + threadIdx.x;
    if (i < N_NODES) outv[i] += blk_base[blockIdx.x];
}

__global__ void unpack_kernel(const unsigned long long* __restrict__ epk,
                              const int* __restrict__ row_ptr,
                              int* __restrict__ src_s, int* __restrict__ dpos) {
    int i = blockIdx.x * 256 + threadIdx.x;
    if (i < N_EDGES) {
        unsigned long long e = epk[i];
        int s = (int)(e & 0xFFFFu);
        int d = (int)((e >> 16) & 0xFFFFu);
        int rank = (int)(e >> 32);
        src_s[i] = s;
        dpos[i] = rank + row_ptr[d];
    }
}

// ================= phase 1: MFMA message kernel — zero-LDS, 4-col-interleaved B,
//                   single 8B packed store per row-group =================

__device__ inline unsigned pack2bf(float x, float y) {
    unsigned short ux = __hip_bfloat16_raw(__float2bfloat16(x)).x;
    unsigned short uy = __hip_bfloat16_raw(__float2bfloat16(y)).x;
    return (unsigned)ux | ((unsigned)uy << 16);
}

__global__ __launch_bounds__(256) void msg_mfma_kernel(
    const __hip_bfloat16* __restrict__ hb, const __hip_bfloat16* __restrict__ Wt,
    const int* __restrict__ rel_ptr, const int* __restrict__ tile_base,
    const int* __restrict__ src_s, const int* __restrict__ dpos,
    __hip_bfloat16* __restrict__ msg) {
    int t = threadIdx.x;
    int w = t >> 6, lane = t & 63;
    int quad = lane >> 4, m16 = lane & 15;
    int wave = blockIdx.x * 4 + w;

    int ntiles = tile_base[N_RELS];
    int tpw = (ntiles + NWAVES - 1) / NWAVES;
    int T = wave * tpw;
    int T1 = T + tpw; if (T1 > ntiles) T1 = ntiles;
    if (T >= T1) return;

    int r = 0;
    while (T >= tile_base[r + 1]) ++r;

    while (T < T1) {
        int chunk_end = tile_base[r + 1]; if (chunk_end > T1) chunk_end = T1;
        int e_base = rel_ptr[r], t_base = tile_base[r];
        int seg_end = rel_ptr[r + 1];

        const __hip_bfloat16* Wr = Wt + (size_t)r * (DIM * DIM);
        short8 bf00 = *(const short8*)(Wr + (4 * m16)     * DIM + quad * 8);
        short8 bf01 = *(const short8*)(Wr + (4 * m16 + 1) * DIM + quad * 8);
        short8 bf02 = *(const short8*)(Wr + (4 * m16 + 2) * DIM + quad * 8);
        short8 bf03 = *(const short8*)(Wr + (4 * m16 + 3) * DIM + quad * 8);
        short8 bf10 = *(const short8*)(Wr + (4 * m16)     * DIM + 32 + quad * 8);
        short8 bf11 = *(const short8*)(Wr + (4 * m16 + 1) * DIM + 32 + quad * 8);
        short8 bf12 = *(const short8*)(Wr + (4 * m16 + 2) * DIM + 32 + quad * 8);
        short8 bf13 = *(const short8*)(Wr + (4 * m16 + 3) * DIM + 32 + quad * 8);

        auto loadidx = [&](int TT, int& sv, int& dp) {
            int TC = TT < chunk_end ? TT : chunk_end - 1;
            int i = e_base + (TC - t_base) * 16 + lane;
            if (i >= N_EDGES) i = N_EDGES - 1;
            sv = src_s[i]; dp = dpos[i];
        };
        auto gatherA = [&](int sv, short8& x0, short8& x1) {
            int s = __shfl(sv, m16);
            const __hip_bfloat16* hp = hb + (size_t)s * DIM + quad * 8;
            x0 = *(const short8*)hp;
            x1 = *(const short8*)(hp + 32);
        };

        int sv0, dp0, sv1, dp1, sv2, dp2;
        short8 a0c, a1c, a0n, a1n;
        loadidx(T,     sv0, dp0);
        loadidx(T + 1, sv1, dp1);
        gatherA(sv0, a0c, a1c);

        for (; T < chunk_end; ++T) {
            loadidx(T + 2, sv2, dp2);
            gatherA(sv1, a0n, a1n);

            int e0 = e_base + (T - t_base) * 16;
            int rows = seg_end - e0; if (rows > 16) rows = 16;

            f32x4 c0 = {0.f, 0.f, 0.f, 0.f}, c1 = c0, c2 = c0, c3 = c0;
            c0 = __builtin_amdgcn_mfma_f32_16x16x32_bf16(a0c, bf00, c0, 0, 0, 0);
            c1 = __builtin_amdgcn_mfma_f32_16x16x32_bf16(a0c, bf01, c1, 0, 0, 0);
            c2 = __builtin_amdgcn_mfma_f32_16x16x32_bf16(a0c, bf02, c2, 0, 0, 0);
            c3 = __builtin_amdgcn_mfma_f32_16x16x32_bf16(a0c, bf03, c3, 0, 0, 0);
            c0 = __builtin_amdgcn_mfma_f32_16x16x32_bf16(a1c, bf10, c0, 0, 0, 0);
            c1 = __builtin_amdgcn_mfma_f32_16x16x32_bf16(a1c, bf11, c1, 0, 0, 0);
            c2 = __builtin_amdgcn_mfma_f32_16x16x32_bf16(a1c, bf12, c2, 0, 0, 0);
            c3 = __builtin_amdgcn_mfma_f32_16x16x32_bf16(a1c, bf13, c3, 0, 0, 0);

            int dpr[4];
            #pragma unroll
            for (int g = 0; g < 4; ++g) dpr[g] = __shfl(dp0, quad * 4 + g);

            #pragma unroll
            for (int g = 0; g < 4; ++g) {
                if (quad * 4 + g < rows) {
                    uint2 pk;
                    pk.x = pack2bf(c0[g], c1[g]);
                    pk.y = pack2bf(c2[g], c3[g]);
                    *(uint2*)(msg + (size_t)dpr[g] * DIM + 4 * m16) = pk;
                }
            }

            sv0 = sv1; dp0 = dp1; sv1 = sv2; dp1 = dp2;
            a0c = a0n; a1c = a1n;
        }
        ++r;
        while (T < T1 && T >= tile_base[r + 1]) ++r;
    }
}

// ================= phase 2: vectorized pull-aggregate + bias + ReLU =================

__global__ __launch_bounds__(256) void agg_kernel(
    const __hip_bfloat16* __restrict__ msg, const int* __restrict__ row_ptr,
    const int* __restrict__ cnt_d, const float* __restrict__ b,
    __hip_bfloat16* __restrict__ hout) {
    int wave = blockIdx.x * 4 + (threadIdx.x >> 6);
    int lane = threadIdx.x & 63;
    if (wave >= N_NODES) return;
    int j0 = row_ptr[wave];
    int n  = cnt_d[wave];
    int rgrp = lane >> 3, dgrp = lane & 7;

    float a[8] = {0.f, 0.f, 0.f, 0.f, 0.f, 0.f, 0.f, 0.f};
    for (int jj = 0; jj < n; jj += 8) {
        int row = jj + rgrp;
        if (row < n) {
            uint4 d = *(const uint4*)(msg + (size_t)(j0 + row) * DIM + dgrp * 8);
            a[0] += __uint_as_float(d.x << 16);
            a[1] += __uint_as_float(d.x & 0xffff0000u);
            a[2] += __uint_as_float(d.y << 16);
            a[3] += __uint_as_float(d.y & 0xffff0000u);
            a[4] += __uint_as_float(d.z << 16);
            a[5] += __uint_as_float(d.z & 0xffff0000u);
            a[6] += __uint_as_float(d.w << 16);
            a[7] += __uint_as_float(d.w & 0xffff0000u);
        }
    }
    #pragma unroll
    for (int i = 0; i < 8; ++i) {
        a[i] += __shfl_xor(a[i], 8);
        a[i] += __shfl_xor(a[i], 16);
        a[i] += __shfl_xor(a[i], 32);
    }
    if (rgrp == 0) {
        unsigned short us[8];
        #pragma unroll
        for (int i = 0; i < 8; ++i) {
            float v = a[i] + b[dgrp * 8 + i];
            us[i] = __hip_bfloat16_raw(__float2bfloat16(v > 0.f ? v : 0.f)).x;
        }
        *(uint4*)(hout + (size_t)wave * DIM + dgrp * 8) = *(const uint4*)us;
    }
}

// ================= fused pool + FC x3 + prediction head =================

__global__ __launch_bounds__(256) void poolfc_kernel(
    const __hip_bfloat16* __restrict__ h, const int* __restrict__ g_ptr,
    const int* __restrict__ cnt_g,
    const float* __restrict__ W1, const float* __restrict__ b1,
    const float* __restrict__ W2, const float* __restrict__ b2,
    const float* __restrict__ W3, const float* __restrict__ b3,
    const float* __restrict__ pW, const float* __restrict__ pb,
    float* __restrict__ out) {
    int wave = blockIdx.x * 4 + (threadIdx.x >> 6);
    int lane = threadIdx.x & 63;
    if (wave >= N_GRAPHS) return;
    int j0 = g_ptr[wave];
    int n  = cnt_g[wave];
    int rgrp = lane >> 3, dgrp = lane & 7;

    float a[8] = {0.f, 0.f, 0.f, 0.f, 0.f, 0.f, 0.f, 0.f};
    for (int jj = 0; jj < n; jj += 8) {
        int row = jj + rgrp;
        if (row < n) {
            uint4 d = *(const uint4*)(h + (size_t)(j0 + row) * DIM + dgrp * 8);
            a[0] += __uint_as_float(d.x << 16);
            a[1] += __uint_as_float(d.x & 0xffff0000u);
            a[2] += __uint_as_float(d.y << 16);
            a[3] += __uint_as_float(d.y & 0xffff0000u);
            a[4] += __uint_as_float(d.z << 16);
            a[5] += __uint_as_float(d.z & 0xffff0000u);
            a[6] += __uint_as_float(d.w << 16);
            a[7] += __uint_as_float(d.w & 0xffff0000u);
        }
    }
    #pragma unroll
    for (int i = 0; i < 8; ++i) {
        a[i] += __shfl_xor(a[i], 8);
        a[i] += __shfl_xor(a[i], 16);
        a[i] += __shfl_xor(a[i], 32);
    }
    float v;
    {
        float acc = b1[lane];
        #pragma unroll
        for (int o = 0; o < 8; ++o)
            #pragma unroll
            for (int q = 0; q < 8; ++q)
                acc += __shfl(a[o], q) * W1[(q * 8 + o) * DIM + lane];
        v = acc > 0.f ? acc : 0.f;
    }
    {
        float acc = b2[lane];
        #pragma unroll
        for (int d = 0; d < DIM; ++d)
            acc += __shfl(v, d) * W2[d * DIM + lane];
        v = acc > 0.f ? acc : 0.f;
    }
    {
        float acc = b3[lane];
        #pragma unroll
        for (int d = 0; d < DIM; ++d)
            acc += __shfl(v, d) * W3[d * DIM + lane];
        v = acc > 0.f ? acc : 0.f;
    }
    float p0 = v * pW[lane * 2 + 0];
    float p1 = v * pW[lane * 2 + 1];
    #pragma unroll
    for (int off = 32; off > 0; off >>= 1) {
        p0 += __shfl_down(p0, off);
        p1 += __shfl_down(p1, off);
    }
    if (lane == 0) {
        out[wave * 2 + 0] = p0 + pb[0];
        out[wave * 2 + 1] = p1 + pb[1];
    }
}

// ================= launch =================

extern "C" void kernel_launch(void* const* d_in, const int* in_sizes, int n_in,
                              void* d_out, int out_size, void* d_ws, size_t ws_size,
                              hipStream_t stream) {
    const float* node_feats = (const float*)d_in[0];
    const int*   etypes     = (const int*)d_in[1];
    const int*   src        = (const int*)d_in[2];
    const int*   dst        = (const int*)d_in[3];
    const int*   graph_ids  = (const int*)d_in[4];
    const float* W1 = (const float*)d_in[5];
    const float* b1 = (const float*)d_in[6];
    const float* W2 = (const float*)d_in[7];
    const float* b2 = (const float*)d_in[8];
    const float* W3 = (const float*)d_in[9];
    const float* b3 = (const float*)d_in[10];
    const float* fcW1 = (const float*)d_in[11];
    const float* fcb1 = (const float*)d_in[12];
    const float* fcW2 = (const float*)d_in[13];
    const float* fcb2 = (const float*)d_in[14];
    const float* fcW3 = (const float*)d_in[15];
    const float* fcb3 = (const float*)d_in[16];
    const float* pW = (const float*)d_in[17];
    const float* pb = (const float*)d_in[18];
    float* out = (float*)d_out;

    // workspace carve-up (256B aligned)
    char* p = (char*)d_ws;
    auto alloc = [&](size_t bytes) -> void* {
        void* r = (void*)p;
        p += (bytes + 255) & ~(size_t)255;
        return r;
    };
    int* blk_hist  = (int*)alloc((size_t)SORT_BLOCKS * N_RELS * sizeof(int));
    int* blk_off   = (int*)alloc((size_t)SORT_BLOCKS * N_RELS * sizeof(int));
    int* rel_ptr   = (int*)alloc((N_RELS + 1) * sizeof(int));
    int* rel_tot   = (int*)alloc(N_RELS * sizeof(int));
    int* tile_base = (int*)alloc((N_RELS + 1) * sizeof(int));
    unsigned long long* epk = (unsigned long long*)alloc((size_t)N_EDGES * sizeof(unsigned long long));
    int* src_s     = (int*)alloc((size_t)N_EDGES * sizeof(int));
    int* dpos      = (int*)alloc((size_t)N_EDGES * sizeof(int));
    int* cnt_d     = (int*)alloc((size_t)N_NODES * sizeof(int));
    int* row_ptr   = (int*)alloc((size_t)N_NODES * sizeof(int));
    int* blk_tot   = (int*)alloc(NSCAN_BLKS * sizeof(int));
    int* blk_base  = (int*)alloc(NSCAN_BLKS * sizeof(int));
    int* cnt_g     = (int*)alloc(N_GRAPHS * sizeof(int));
    int* g_ptr     = (int*)alloc(N_GRAPHS * sizeof(int));
    __hip_bfloat16* hb0 = (__hip_bfloat16*)alloc((size_t)N_NODES * DIM * sizeof(__hip_bfloat16));
    __hip_bfloat16* hb1 = (__hip_bfloat16*)alloc((size_t)N_NODES * DIM * sizeof(__hip_bfloat16));
    __hip_bfloat16* Wt1 = (__hip_bfloat16*)alloc((size_t)N_RELS * DIM * DIM * sizeof(__hip_bfloat16));
    __hip_bfloat16* Wt2 = (__hip_bfloat16*)alloc((size_t)N_RELS * DIM * DIM * sizeof(__hip_bfloat16));
    __hip_bfloat16* Wt3 = (__hip_bfloat16*)alloc((size_t)N_RELS * DIM * DIM * sizeof(__hip_bfloat16));
    __hip_bfloat16* msg = (__hip_bfloat16*)alloc((size_t)N_EDGES * DIM * sizeof(__hip_bfloat16));

    const int EBLK = (N_EDGES + 255) / 256;              // 3125
    const int CBLK = (N_NODES * DIM / 4 + 255) / 256;    // 3125
    const int AGG_BLOCKS = (N_NODES + 3) / 4;            // 12500

    // ---- prep ----
    conv_h_zero_kernel<<<CBLK, 256, 0, stream>>>(node_feats, hb0, cnt_d, cnt_g);
    wconv_kernel<<<3 * N_RELS, 256, 0, stream>>>(W1, W2, W3, Wt1, Wt2, Wt3);
    hist_all_kernel<<<SORT_BLOCKS, 256, 0, stream>>>(etypes, graph_ids, blk_hist, cnt_g);
    relscan_kernel<<<N_RELS, 256, 0, stream>>>(blk_hist, blk_off, rel_tot);
    reltop_kernel<<<1, 64, 0, stream>>>(rel_tot, rel_ptr, tile_base);
    scatter2_kernel<<<SORT_BLOCKS, 256, 0, stream>>>(etypes, src, dst, blk_hist, blk_off,
                                                     rel_ptr, epk, cnt_d);
    scanblk_kernel<<<NSCAN_BLKS, SCAN_BLK, 0, stream>>>(cnt_d, row_ptr, blk_tot);
    scantop_gid_kernel<<<2, 64, 0, stream>>>(blk_tot, blk_base, cnt_g, g_ptr);
    scanadd_kernel<<<NSCAN_BLKS, SCAN_BLK, 0, stream>>>(row_ptr, blk_base);
    unpack_kernel<<<EBLK, 256, 0, stream>>>(epk, row_ptr, src_s, dpos);

    // ---- 3 RGCN layers ----
    msg_mfma_kernel<<<MSG_BLOCKS, 256, 0, stream>>>(hb0, Wt1, rel_ptr, tile_base,
                                                    src_s, dpos, msg);
    agg_kernel<<<AGG_BLOCKS, 256, 0, stream>>>(msg, row_ptr, cnt_d, b1, hb1);

    msg_mfma_kernel<<<MSG_BLOCKS, 256, 0, stream>>>(hb1, Wt2, rel_ptr, tile_base,
                                                    src_s, dpos, msg);
    agg_kernel<<<AGG_BLOCKS, 256, 0, stream>>>(msg, row_ptr, cnt_d, b2, hb0);

    msg_mfma_kernel<<<MSG_BLOCKS, 256, 0, stream>>>(hb0, Wt3, rel_ptr, tile_base,
                                                    src_s, dpos, msg);
    agg_kernel<<<AGG_BLOCKS, 256, 0, stream>>>(msg, row_ptr, cnt_d, b3, hb1);

    // ---- fused pool + FC head ----
    poolfc_kernel<<<(N_GRAPHS + 3) / 4, 256, 0, stream>>>(hb1, g_ptr, cnt_g,
                                                          fcW1, fcb1, fcW2, fcb2,
                                                          fcW3, fcb3, pW, pb, out);
}

// Round 5
// 366.022 us; speedup vs baseline: 1.1246x; 1.0476x over previous
//
#include <hip/hip_runtime.h>
#include <hip/hip_bf16.h>

#define N_NODES 50000
#define N_EDGES 800000
#define N_RELS 65
#define DIM 64
#define N_GRAPHS 512

#define SORT_BLOCKS 1024
#define CHUNK ((N_EDGES + SORT_BLOCKS - 1) / SORT_BLOCKS)  // 782

#define SCAN_BLK 512
#define NSCAN_BLKS ((N_NODES + SCAN_BLK - 1) / SCAN_BLK)   // 98

#define MSG_BLOCKS 2048
#define NWAVES (MSG_BLOCKS * 4)

typedef __attribute__((ext_vector_type(8))) short short8;
typedef __attribute__((ext_vector_type(4))) float f32x4;

// ================= prep (fused): h-convert + zero counters + rel-hist + W transpose =================

__global__ __launch_bounds__(256) void prep_kernel(
    const float* __restrict__ x, const int* __restrict__ et,
    __hip_bfloat16* __restrict__ y, int* __restrict__ cnt_d,
    int* __restrict__ blk_hist,
    const float* __restrict__ W1, const float* __restrict__ W2,
    const float* __restrict__ W3,
    __hip_bfloat16* __restrict__ Wt1, __hip_bfloat16* __restrict__ Wt2,
    __hip_bfloat16* __restrict__ Wt3,
    int* __restrict__ done_flags) {
    __shared__ int lh[N_RELS];
    __shared__ float tile[64][65];
    int t = threadIdx.x, b = blockIdx.x;
    int gtid = b * 256 + t;

    // zero counters (consumed by later kernels only)
    if (gtid < N_NODES) cnt_d[gtid] = 0;
    if (gtid < 2) done_flags[gtid] = 0;

    // per-block relation histogram of this block's edge chunk
    if (t < N_RELS) lh[t] = 0;
    __syncthreads();
    int lo = b * CHUNK;
    int hi = lo + CHUNK; if (hi > N_EDGES) hi = N_EDGES;
    for (int i = lo + t; i < hi; i += 256)
        atomicAdd(&lh[et[i]], 1);

    // grid-stride h conversion (f32 -> bf16, vectorized)
    for (int i = gtid; i < (N_NODES * DIM) / 4; i += SORT_BLOCKS * 256) {
        float4 v = *(const float4*)(x + (size_t)i * 4);
        unsigned short us[4];
        us[0] = __hip_bfloat16_raw(__float2bfloat16(v.x)).x;
        us[1] = __hip_bfloat16_raw(__float2bfloat16(v.y)).x;
        us[2] = __hip_bfloat16_raw(__float2bfloat16(v.z)).x;
        us[3] = __hip_bfloat16_raw(__float2bfloat16(v.w)).x;
        *(ushort4*)(y + (size_t)i * 4) = *(const ushort4*)us;
    }

    // W transpose+convert: blocks 0..194 do one rel tile each (LDS-tiled, coalesced)
    if (b < 3 * N_RELS) {
        int which = b / N_RELS, r = b - which * N_RELS;
        const float* W = (which == 0) ? W1 : (which == 1) ? W2 : W3;
        __hip_bfloat16* Wt = (which == 0) ? Wt1 : (which == 1) ? Wt2 : Wt3;
        for (int i = t; i < 4096; i += 256) {
            int row = i >> 6, col = i & 63;
            tile[row][col] = W[(size_t)r * 4096 + i];
        }
        __syncthreads();
        for (int i = t; i < 4096; i += 256) {
            int row = i >> 6, col = i & 63;
            Wt[(size_t)r * 4096 + i] = __float2bfloat16(tile[col][row]);
        }
    }

    __syncthreads();
    if (t < N_RELS) blk_hist[t * SORT_BLOCKS + b] = lh[t];
}

// ================= relscan: per-relation block-offset scan; last block does reltop =================

__global__ __launch_bounds__(256) void relscan_kernel(const int* __restrict__ blk_hist,
                                                      int* __restrict__ blk_off,
                                                      int* __restrict__ rel_tot,
                                                      int* __restrict__ rel_ptr,
                                                      int* __restrict__ tile_base,
                                                      int* __restrict__ done) {
    __shared__ int wsum[4];
    int r = blockIdx.x;
    int t = threadIdx.x;
    int w = t >> 6, lane = t & 63;
    const int PER = SORT_BLOCKS / 256;  // 4
    int4 v0 = *(const int4*)(blk_hist + (size_t)r * SORT_BLOCKS + t * PER);
    int vals[4] = {v0.x, v0.y, v0.z, v0.w};
    int s = 0;
    #pragma unroll
    for (int j = 0; j < PER; ++j) s += vals[j];
    int x = s;
    #pragma unroll
    for (int off = 1; off < 64; off <<= 1) {
        int y = __shfl_up(x, off);
        if (lane >= off) x += y;
    }
    if (lane == 63) wsum[w] = x;
    __syncthreads();
    int base = 0;
    for (int i = 0; i < w; ++i) base += wsum[i];
    int run = base + x - s;
    int out[4];
    #pragma unroll
    for (int j = 0; j < PER; ++j) { out[j] = run; run += vals[j]; }
    *(int4*)(blk_off + (size_t)r * SORT_BLOCKS + t * PER) = *(const int4*)&out[0];

    if (t == 255) {
        __hip_atomic_store(&rel_tot[r], base + x, __ATOMIC_RELAXED, __HIP_MEMORY_SCOPE_AGENT);
        __threadfence();
        int ticket = atomicAdd(done, 1);
        if (ticket == N_RELS - 1) {          // last block: serial cross-relation scan
            int ss = 0, tt = 0;
            for (int q = 0; q < N_RELS; ++q) {
                int v = __hip_atomic_load(&rel_tot[q], __ATOMIC_RELAXED,
                                          __HIP_MEMORY_SCOPE_AGENT);
                rel_ptr[q] = ss; ss += v;
                tile_base[q] = tt; tt += (v + 15) >> 4;
            }
            rel_ptr[N_RELS] = N_EDGES;
            tile_base[N_RELS] = tt;
        }
    }
}

// ================= scatter: LDS-staged counting sort + fused rank atomic =================

__global__ __launch_bounds__(256) void scatter2_kernel(
    const int* __restrict__ et, const int* __restrict__ src,
    const int* __restrict__ dst, const int* __restrict__ blk_hist,
    const int* __restrict__ blk_off, const int* __restrict__ rel_ptr,
    unsigned long long* __restrict__ epk, int* __restrict__ cnt_d) {
    __shared__ unsigned long long buf[CHUNK];
    __shared__ unsigned char relof[CHUNK];
    __shared__ int loff[N_RELS + 1];
    __shared__ int lcur[N_RELS];
    __shared__ int gbase[N_RELS];
    int t = threadIdx.x, b = blockIdx.x;

    if (t < 64) {
        int v = blk_hist[t * SORT_BLOCKS + b];
        int x = v;
        #pragma unroll
        for (int off = 1; off < 64; off <<= 1) {
            int y = __shfl_up(x, off);
            if (t >= off) x += y;
        }
        loff[t] = x - v;
        lcur[t] = x - v;
        gbase[t] = rel_ptr[t] + blk_off[t * SORT_BLOCKS + b];
        if (t == 63) { loff[64] = x; lcur[64] = x; }
    } else if (t == 64) {
        gbase[64] = rel_ptr[64] + blk_off[64 * SORT_BLOCKS + b];
    }
    __syncthreads();

    int lo = b * CHUNK;
    int hi = lo + CHUNK; if (hi > N_EDGES) hi = N_EDGES;
    int nloc = hi - lo;

    #pragma unroll
    for (int k = 0; k < 4; ++k) {
        int i = lo + t + k * 256;
        if (i < hi) {
            int r = et[i], d = dst[i];
            unsigned s = (unsigned)src[i];
            int rank = atomicAdd(&cnt_d[d], 1);      // degree AND rank in one atomic
            int pl = atomicAdd(&lcur[r], 1);
            unsigned lo32 = s | ((unsigned)d << 16);
            buf[pl] = (unsigned long long)lo32 |
                      ((unsigned long long)(unsigned)rank << 32);
            relof[pl] = (unsigned char)r;
        }
    }
    __syncthreads();

    #pragma unroll
    for (int k = 0; k < 4; ++k) {
        int i = t + k * 256;
        if (i < nloc) {
            int r = relof[i];
            epk[gbase[r] + i - loff[r]] = buf[i];
        }
    }
}

// ================= scanblk: dst CSR partial scan; last block does top scan + g_ptr =================

__global__ __launch_bounds__(SCAN_BLK) void scanblk_kernel(
    const int* __restrict__ cnt, int* __restrict__ outv,
    int* __restrict__ blk_tot, int* __restrict__ blk_base,
    const int* __restrict__ gid, int* __restrict__ g_ptr,
    int* __restrict__ cnt_g, int* __restrict__ done) {
    __shared__ int tmp[SCAN_BLK];
    __shared__ int is_last;
    int t = threadIdx.x;
    int i = blockIdx.x * SCAN_BLK + t;
    int v = (i < N_NODES) ? cnt[i] : 0;
    tmp[t] = v;
    __syncthreads();
    for (int off = 1; off < SCAN_BLK; off <<= 1) {
        int add = (t >= off) ? tmp[t - off] : 0;
        __syncthreads();
        tmp[t] += add;
        __syncthreads();
    }
    if (i < N_NODES) outv[i] = tmp[t] - v;  // block-local exclusive
    if (t == SCAN_BLK - 1) {
        __hip_atomic_store(&blk_tot[blockIdx.x], tmp[t], __ATOMIC_RELAXED,
                           __HIP_MEMORY_SCOPE_AGENT);
        __threadfence();
        int ticket = atomicAdd(done, 1);
        is_last = (ticket == NSCAN_BLKS - 1) ? 1 : 0;
    }
    __syncthreads();
    if (is_last) {
        if (t == 0) {
            int run = 0;
            for (int b2 = 0; b2 < NSCAN_BLKS; ++b2) {
                int v2 = __hip_atomic_load(&blk_tot[b2], __ATOMIC_RELAXED,
                                           __HIP_MEMORY_SCOPE_AGENT);
                blk_base[b2] = run; run += v2;
            }
        }
        // graph segments via binary search (graph_ids is sorted)
        if (t < N_GRAPHS) {
            int g = t;
            int lo2 = 0, hi2 = N_NODES;
            while (lo2 < hi2) { int m = (lo2 + hi2) >> 1; if (gid[m] < g) lo2 = m + 1; else hi2 = m; }
            int a2 = lo2;
            lo2 = 0; hi2 = N_NODES;
            int g1 = g + 1;
            while (lo2 < hi2) { int m = (lo2 + hi2) >> 1; if (gid[m] < g1) lo2 = m + 1; else hi2 = m; }
            g_ptr[g] = a2;
            cnt_g[g] = lo2 - a2;
        }
    }
}

// ================= unpack (+ row_ptr fixup on the fly) =================

__global__ void unpack_kernel(const unsigned long long* __restrict__ epk,
                              const int* __restrict__ outv,
                              const int* __restrict__ blk_base,
                              int* __restrict__ src_s, int* __restrict__ dpos) {
    int i = blockIdx.x * 256 + threadIdx.x;
    if (i < N_EDGES) {
        unsigned long long e = epk[i];
        int s = (int)(e & 0xFFFFu);
        int d = (int)((e >> 16) & 0xFFFFu);
        int rank = (int)(e >> 32);
        src_s[i] = s;
        dpos[i] = rank + outv[d] + blk_base[d >> 9];
    }
}

// ================= phase 1: MFMA message kernel — zero-LDS, 4-col-interleaved B =================

__device__ inline unsigned pack2bf(float x, float y) {
    unsigned short ux = __hip_bfloat16_raw(__float2bfloat16(x)).x;
    unsigned short uy = __hip_bfloat16_raw(__float2bfloat16(y)).x;
    return (unsigned)ux | ((unsigned)uy << 16);
}

__global__ __launch_bounds__(256) void msg_mfma_kernel(
    const __hip_bfloat16* __restrict__ hb, const __hip_bfloat16* __restrict__ Wt,
    const int* __restrict__ rel_ptr, const int* __restrict__ tile_base,
    const int* __restrict__ src_s, const int* __restrict__ dpos,
    __hip_bfloat16* __restrict__ msg) {
    int t = threadIdx.x;
    int w = t >> 6, lane = t & 63;
    int quad = lane >> 4, m16 = lane & 15;
    int wave = blockIdx.x * 4 + w;

    int ntiles = tile_base[N_RELS];
    int tpw = (ntiles + NWAVES - 1) / NWAVES;
    int T = wave * tpw;
    int T1 = T + tpw; if (T1 > ntiles) T1 = ntiles;
    if (T >= T1) return;

    int r = 0;
    while (T >= tile_base[r + 1]) ++r;

    while (T < T1) {
        int chunk_end = tile_base[r + 1]; if (chunk_end > T1) chunk_end = T1;
        int e_base = rel_ptr[r], t_base = tile_base[r];
        int seg_end = rel_ptr[r + 1];

        const __hip_bfloat16* Wr = Wt + (size_t)r * (DIM * DIM);
        short8 bf00 = *(const short8*)(Wr + (4 * m16)     * DIM + quad * 8);
        short8 bf01 = *(const short8*)(Wr + (4 * m16 + 1) * DIM + quad * 8);
        short8 bf02 = *(const short8*)(Wr + (4 * m16 + 2) * DIM + quad * 8);
        short8 bf03 = *(const short8*)(Wr + (4 * m16 + 3) * DIM + quad * 8);
        short8 bf10 = *(const short8*)(Wr + (4 * m16)     * DIM + 32 + quad * 8);
        short8 bf11 = *(const short8*)(Wr + (4 * m16 + 1) * DIM + 32 + quad * 8);
        short8 bf12 = *(const short8*)(Wr + (4 * m16 + 2) * DIM + 32 + quad * 8);
        short8 bf13 = *(const short8*)(Wr + (4 * m16 + 3) * DIM + 32 + quad * 8);

        auto loadidx = [&](int TT, int& sv, int& dp) {
            int TC = TT < chunk_end ? TT : chunk_end - 1;
            int i = e_base + (TC - t_base) * 16 + lane;
            if (i >= N_EDGES) i = N_EDGES - 1;
            sv = src_s[i]; dp = dpos[i];
        };
        auto gatherA = [&](int sv, short8& x0, short8& x1) {
            int s = __shfl(sv, m16);
            const __hip_bfloat16* hp = hb + (size_t)s * DIM + quad * 8;
            x0 = *(const short8*)hp;
            x1 = *(const short8*)(hp + 32);
        };

        int sv0, dp0, sv1, dp1, sv2, dp2;
        short8 a0c, a1c, a0n, a1n;
        loadidx(T,     sv0, dp0);
        loadidx(T + 1, sv1, dp1);
        gatherA(sv0, a0c, a1c);

        for (; T < chunk_end; ++T) {
            loadidx(T + 2, sv2, dp2);
            gatherA(sv1, a0n, a1n);

            int e0 = e_base + (T - t_base) * 16;
            int rows = seg_end - e0; if (rows > 16) rows = 16;

            f32x4 c0 = {0.f, 0.f, 0.f, 0.f}, c1 = c0, c2 = c0, c3 = c0;
            c0 = __builtin_amdgcn_mfma_f32_16x16x32_bf16(a0c, bf00, c0, 0, 0, 0);
            c1 = __builtin_amdgcn_mfma_f32_16x16x32_bf16(a0c, bf01, c1, 0, 0, 0);
            c2 = __builtin_amdgcn_mfma_f32_16x16x32_bf16(a0c, bf02, c2, 0, 0, 0);
            c3 = __builtin_amdgcn_mfma_f32_16x16x32_bf16(a0c, bf03, c3, 0, 0, 0);
            c0 = __builtin_amdgcn_mfma_f32_16x16x32_bf16(a1c, bf10, c0, 0, 0, 0);
            c1 = __builtin_amdgcn_mfma_f32_16x16x32_bf16(a1c, bf11, c1, 0, 0, 0);
            c2 = __builtin_amdgcn_mfma_f32_16x16x32_bf16(a1c, bf12, c2, 0, 0, 0);
            c3 = __builtin_amdgcn_mfma_f32_16x16x32_bf16(a1c, bf13, c3, 0, 0, 0);

            int dpr[4];
            #pragma unroll
            for (int g = 0; g < 4; ++g) dpr[g] = __shfl(dp0, quad * 4 + g);

            #pragma unroll
            for (int g = 0; g < 4; ++g) {
                if (quad * 4 + g < rows) {
                    uint2 pk;
                    pk.x = pack2bf(c0[g], c1[g]);
                    pk.y = pack2bf(c2[g], c3[g]);
                    *(uint2*)(msg + (size_t)dpr[g] * DIM + 4 * m16) = pk;
                }
            }

            sv0 = sv1; dp0 = dp1; sv1 = sv2; dp1 = dp2;
            a0c = a0n; a1c = a1n;
        }
        ++r;
        while (T < T1 && T >= tile_base[r + 1]) ++r;
    }
}

// ================= phase 2: vectorized pull-aggregate + bias + ReLU =================

__global__ __launch_bounds__(256) void agg_kernel(
    const __hip_bfloat16* __restrict__ msg, const int* __restrict__ outv,
    const int* __restrict__ blk_base,
    const int* __restrict__ cnt_d, const float* __restrict__ b,
    __hip_bfloat16* __restrict__ hout) {
    int wave = blockIdx.x * 4 + (threadIdx.x >> 6);
    int lane = threadIdx.x & 63;
    if (wave >= N_NODES) return;
    int j0 = outv[wave] + blk_base[wave >> 9];
    int n  = cnt_d[wave];
    int rgrp = lane >> 3, dgrp = lane & 7;

    float a[8] = {0.f, 0.f, 0.f, 0.f, 0.f, 0.f, 0.f, 0.f};
    for (int jj = 0; jj < n; jj += 8) {
        int row = jj + rgrp;
        if (row < n) {
            uint4 d = *(const uint4*)(msg + (size_t)(j0 + row) * DIM + dgrp * 8);
            a[0] += __uint_as_float(d.x << 16);
            a[1] += __uint_as_float(d.x & 0xffff0000u);
            a[2] += __uint_as_float(d.y << 16);
            a[3] += __uint_as_float(d.y & 0xffff0000u);
            a[4] += __uint_as_float(d.z << 16);
            a[5] += __uint_as_float(d.z & 0xffff0000u);
            a[6] += __uint_as_float(d.w << 16);
            a[7] += __uint_as_float(d.w & 0xffff0000u);
        }
    }
    #pragma unroll
    for (int i = 0; i < 8; ++i) {
        a[i] += __shfl_xor(a[i], 8);
        a[i] += __shfl_xor(a[i], 16);
        a[i] += __shfl_xor(a[i], 32);
    }
    if (rgrp == 0) {
        unsigned short us[8];
        #pragma unroll
        for (int i = 0; i < 8; ++i) {
            float v = a[i] + b[dgrp * 8 + i];
            us[i] = __hip_bfloat16_raw(__float2bfloat16(v > 0.f ? v : 0.f)).x;
        }
        *(uint4*)(hout + (size_t)wave * DIM + dgrp * 8) = *(const uint4*)us;
    }
}

// ================= fused pool + FC x3 + prediction head =================

__global__ __launch_bounds__(256) void poolfc_kernel(
    const __hip_bfloat16* __restrict__ h, const int* __restrict__ g_ptr,
    const int* __restrict__ cnt_g,
    const float* __restrict__ W1, const float* __restrict__ b1,
    const float* __restrict__ W2, const float* __restrict__ b2,
    const float* __restrict__ W3, const float* __restrict__ b3,
    const float* __restrict__ pW, const float* __restrict__ pb,
    float* __restrict__ out) {
    int wave = blockIdx.x * 4 + (threadIdx.x >> 6);
    int lane = threadIdx.x & 63;
    if (wave >= N_GRAPHS) return;
    int j0 = g_ptr[wave];
    int n  = cnt_g[wave];
    int rgrp = lane >> 3, dgrp = lane & 7;

    float a[8] = {0.f, 0.f, 0.f, 0.f, 0.f, 0.f, 0.f, 0.f};
    for (int jj = 0; jj < n; jj += 8) {
        int row = jj + rgrp;
        if (row < n) {
            uint4 d = *(const uint4*)(h + (size_t)(j0 + row) * DIM + dgrp * 8);
            a[0] += __uint_as_float(d.x << 16);
            a[1] += __uint_as_float(d.x & 0xffff0000u);
            a[2] += __uint_as_float(d.y << 16);
            a[3] += __uint_as_float(d.y & 0xffff0000u);
            a[4] += __uint_as_float(d.z << 16);
            a[5] += __uint_as_float(d.z & 0xffff0000u);
            a[6] += __uint_as_float(d.w << 16);
            a[7] += __uint_as_float(d.w & 0xffff0000u);
        }
    }
    #pragma unroll
    for (int i = 0; i < 8; ++i) {
        a[i] += __shfl_xor(a[i], 8);
        a[i] += __shfl_xor(a[i], 16);
        a[i] += __shfl_xor(a[i], 32);
    }
    float v;
    {
        float acc = b1[lane];
        #pragma unroll
        for (int o = 0; o < 8; ++o)
            #pragma unroll
            for (int q = 0; q < 8; ++q)
                acc += __shfl(a[o], q) * W1[(q * 8 + o) * DIM + lane];
        v = acc > 0.f ? acc : 0.f;
    }
    {
        float acc = b2[lane];
        #pragma unroll
        for (int d = 0; d < DIM; ++d)
            acc += __shfl(v, d) * W2[d * DIM + lane];
        v = acc > 0.f ? acc : 0.f;
    }
    {
        float acc = b3[lane];
        #pragma unroll
        for (int d = 0; d < DIM; ++d)
            acc += __shfl(v, d) * W3[d * DIM + lane];
        v = acc > 0.f ? acc : 0.f;
    }
    float p0 = v * pW[lane * 2 + 0];
    float p1 = v * pW[lane * 2 + 1];
    #pragma unroll
    for (int off = 32; off > 0; off >>= 1) {
        p0 += __shfl_down(p0, off);
        p1 += __shfl_down(p1, off);
    }
    if (lane == 0) {
        out[wave * 2 + 0] = p0 + pb[0];
        out[wave * 2 + 1] = p1 + pb[1];
    }
}

// ================= launch =================

extern "C" void kernel_launch(void* const* d_in, const int* in_sizes, int n_in,
                              void* d_out, int out_size, void* d_ws, size_t ws_size,
                              hipStream_t stream) {
    const float* node_feats = (const float*)d_in[0];
    const int*   etypes     = (const int*)d_in[1];
    const int*   src        = (const int*)d_in[2];
    const int*   dst        = (const int*)d_in[3];
    const int*   graph_ids  = (const int*)d_in[4];
    const float* W1 = (const float*)d_in[5];
    const float* b1 = (const float*)d_in[6];
    const float* W2 = (const float*)d_in[7];
    const float* b2 = (const float*)d_in[8];
    const float* W3 = (const float*)d_in[9];
    const float* b3 = (const float*)d_in[10];
    const float* fcW1 = (const float*)d_in[11];
    const float* fcb1 = (const float*)d_in[12];
    const float* fcW2 = (const float*)d_in[13];
    const float* fcb2 = (const float*)d_in[14];
    const float* fcW3 = (const float*)d_in[15];
    const float* fcb3 = (const float*)d_in[16];
    const float* pW = (const float*)d_in[17];
    const float* pb = (const float*)d_in[18];
    float* out = (float*)d_out;

    // workspace carve-up (256B aligned)
    char* p = (char*)d_ws;
    auto alloc = [&](size_t bytes) -> void* {
        void* r = (void*)p;
        p += (bytes + 255) & ~(size_t)255;
        return r;
    };
    int* blk_hist  = (int*)alloc((size_t)SORT_BLOCKS * N_RELS * sizeof(int));
    int* blk_off   = (int*)alloc((size_t)SORT_BLOCKS * N_RELS * sizeof(int));
    int* rel_ptr   = (int*)alloc((N_RELS + 1) * sizeof(int));
    int* rel_tot   = (int*)alloc(N_RELS * sizeof(int));
    int* tile_base = (int*)alloc((N_RELS + 1) * sizeof(int));
    unsigned long long* epk = (unsigned long long*)alloc((size_t)N_EDGES * sizeof(unsigned long long));
    int* src_s     = (int*)alloc((size_t)N_EDGES * sizeof(int));
    int* dpos      = (int*)alloc((size_t)N_EDGES * sizeof(int));
    int* cnt_d     = (int*)alloc((size_t)N_NODES * sizeof(int));
    int* outv      = (int*)alloc((size_t)N_NODES * sizeof(int));
    int* blk_tot   = (int*)alloc(NSCAN_BLKS * sizeof(int));
    int* blk_base  = (int*)alloc(NSCAN_BLKS * sizeof(int));
    int* cnt_g     = (int*)alloc(N_GRAPHS * sizeof(int));
    int* g_ptr     = (int*)alloc(N_GRAPHS * sizeof(int));
    int* done_flags= (int*)alloc(2 * sizeof(int));
    __hip_bfloat16* hb0 = (__hip_bfloat16*)alloc((size_t)N_NODES * DIM * sizeof(__hip_bfloat16));
    __hip_bfloat16* hb1 = (__hip_bfloat16*)alloc((size_t)N_NODES * DIM * sizeof(__hip_bfloat16));
    __hip_bfloat16* Wt1 = (__hip_bfloat16*)alloc((size_t)N_RELS * DIM * DIM * sizeof(__hip_bfloat16));
    __hip_bfloat16* Wt2 = (__hip_bfloat16*)alloc((size_t)N_RELS * DIM * DIM * sizeof(__hip_bfloat16));
    __hip_bfloat16* Wt3 = (__hip_bfloat16*)alloc((size_t)N_RELS * DIM * DIM * sizeof(__hip_bfloat16));
    __hip_bfloat16* msg = (__hip_bfloat16*)alloc((size_t)N_EDGES * DIM * sizeof(__hip_bfloat16));

    const int EBLK = (N_EDGES + 255) / 256;              // 3125
    const int AGG_BLOCKS = (N_NODES + 3) / 4;            // 12500

    // ---- prep (5 dispatches total before layers) ----
    prep_kernel<<<SORT_BLOCKS, 256, 0, stream>>>(node_feats, etypes, hb0, cnt_d, blk_hist,
                                                 W1, W2, W3, Wt1, Wt2, Wt3, done_flags);
    relscan_kernel<<<N_RELS, 256, 0, stream>>>(blk_hist, blk_off, rel_tot,
                                               rel_ptr, tile_base, &done_flags[0]);
    scatter2_kernel<<<SORT_BLOCKS, 256, 0, stream>>>(etypes, src, dst, blk_hist, blk_off,
                                                     rel_ptr, epk, cnt_d);
    scanblk_kernel<<<NSCAN_BLKS, SCAN_BLK, 0, stream>>>(cnt_d, outv, blk_tot, blk_base,
                                                        graph_ids, g_ptr, cnt_g,
                                                        &done_flags[1]);
    unpack_kernel<<<EBLK, 256, 0, stream>>>(epk, outv, blk_base, src_s, dpos);

    // ---- 3 RGCN layers ----
    msg_mfma_kernel<<<MSG_BLOCKS, 256, 0, stream>>>(hb0, Wt1, rel_ptr, tile_base,
                                                    src_s, dpos, msg);
    agg_kernel<<<AGG_BLOCKS, 256, 0, stream>>>(msg, outv, blk_base, cnt_d, b1, hb1);

    msg_mfma_kernel<<<MSG_BLOCKS, 256, 0, stream>>>(hb1, Wt2, rel_ptr, tile_base,
                                                    src_s, dpos, msg);
    agg_kernel<<<AGG_BLOCKS, 256, 0, stream>>>(msg, outv, blk_base, cnt_d, b2, hb0);

    msg_mfma_kernel<<<MSG_BLOCKS, 256, 0, stream>>>(hb0, Wt3, rel_ptr, tile_base,
                                                    src_s, dpos, msg);
    agg_kernel<<<AGG_BLOCKS, 256, 0, stream>>>(msg, outv, blk_base, cnt_d, b3, hb1);

    // ---- fused pool + FC head ----
    poolfc_kernel<<<(N_GRAPHS + 3) / 4, 256, 0, stream>>>(hb1, g_ptr, cnt_g,
                                                          fcW1, fcb1, fcW2, fcb2,
                                                          fcW3, fcb3, pW, pb, out);
}